// Round 8
// baseline (251200.757 us; speedup 1.0000x reference)
//
#include <hip/hip_runtime.h>
#include <hip/hip_bf16.h>

#define NB    128
#define LSEQ  512
#define HIDN  512
#define EMB   256
#define GRID_ALL 256    // one block per CU (forced by 128KB LDS); 32 per XCD
#define TEAM  32        // blocks per team; team == XCD; rank owns hidden units [rank*16, +16)
#define DEADLINE_TICKS 25000000ull   // s_memrealtime watchdog: finite even on sync failure

typedef __attribute__((ext_vector_type(8))) short  short8;   // MFMA A/B frag (8 bf16)
typedef __attribute__((ext_vector_type(4))) float  floatx4;  // MFMA C/D frag
typedef __attribute__((ext_vector_type(4))) unsigned int uintx4;

__device__ __forceinline__ unsigned short f2bf(float f) {   // RNE
  unsigned u = __builtin_bit_cast(unsigned, f);
  unsigned r = u + 0x7fffu + ((u >> 16) & 1u);
  return (unsigned short)(r >> 16);
}
__device__ __forceinline__ unsigned bfpair(float lo, float hi) {
  unsigned a = __builtin_bit_cast(unsigned, lo) + 0x8000u;
  unsigned b = __builtin_bit_cast(unsigned, hi) + 0x8000u;
  return __builtin_amdgcn_perm(b, a, 0x07060302u);
}
__device__ __forceinline__ short8 pack8(float4 u, float4 v) {
  union { short8 s; uintx4 w; } cv;
  cv.w[0] = bfpair(u.x, u.y); cv.w[1] = bfpair(u.z, u.w);
  cv.w[2] = bfpair(v.x, v.y); cv.w[3] = bfpair(v.z, v.w);
  return cv.s;
}
__device__ __forceinline__ float sigmoid_f(float x) { return 1.f / (1.f + __expf(-x)); }
__device__ __forceinline__ float tanh_f(float x) {
  float e = __expf(2.f * x);
  return 1.f - 2.f / (e + 1.f);
}

// sc0 load: bypass L1 ONLY -> served by the XCD-local L2, the coherence point
// for CUs on the same XCD (CDNA L1 is write-through; peer plain-stores are
// committed to L2 after their vmcnt drain). Proven correct in R5.
__device__ __forceinline__ short8 ld16_sc0(const void* p) {
  short8 d;
  asm volatile("global_load_dwordx4 %0, %1, off sc0"
               : "=v"(d) : "v"(p) : "memory");
  return d;
}
__device__ __forceinline__ int ld_flag_sc0(const int* p) {
  int v;
  asm volatile("global_load_dword %0, %1, off sc0\n\t"
               "s_waitcnt vmcnt(0)"
               : "=v"(v) : "v"(p) : "memory");
  return v;
}
__device__ __forceinline__ unsigned long long rtclock() {
  unsigned long long v;
  asm volatile("s_memrealtime %0\n\ts_waitcnt lgkmcnt(0)" : "=s"(v));
  return v;
}

// xe[t][n][e] = bf16(E[X[n][t]][e]) — time-major, k-contiguous
__global__ void prep_x_kernel(const int* __restrict__ X, const float* __restrict__ E,
                              unsigned short* __restrict__ xe) {
  int t = blockIdx.x, n = blockIdx.y;
  int row = X[(size_t)n * LSEQ + t];
  float4 v = ((const float4*)(E + (size_t)row * EMB))[threadIdx.x];
  ushort4 o;
  o.x = f2bf(v.x); o.y = f2bf(v.y); o.z = f2bf(v.z); o.w = f2bf(v.w);
  *(ushort4*)(xe + ((size_t)t * NB + n) * EMB + threadIdx.x * 4) = o;
}

// ---- main recurrence: 8 INDEPENDENT single-XCD teams -----------------------
// R5 proved traffic volume & path latency aren't the limit: FETCH/WRITE
// collapsed 20x with zero time change. The invariant across all ~11us/step
// structures was per-CU h ingest (every block pulled ALL 128 rows). Batch
// rows are independent recurrences -> split N=128 into 8 teams of 16 rows,
// one team per XCD (team = HW_REG_XCC_ID; rank = per-XCD ticket order).
// Per-CU per-step: 16KB h pull + 16KB LDS tile + 24 MFMA. Teams never sync
// with each other; all exchange stays in the team's own L2 (plain
// write-through stores + sc0 loads). Every spin is deadline-bounded
// (s_memrealtime): a residency/sync failure yields a finite wrong answer,
// never a GPU wedge.
template <bool USE_XE>
__global__ void __launch_bounds__(256, 1)
lstm_main(const int* __restrict__ X, const float* __restrict__ E,
          const unsigned short* __restrict__ xe,
          const float* __restrict__ Wi, const float* __restrict__ bi,
          const float* __restrict__ Wf, const float* __restrict__ bf_,
          const float* __restrict__ Wo, const float* __restrict__ bo,
          const float* __restrict__ Wh, const float* __restrict__ bh,
          float* __restrict__ out, unsigned short* __restrict__ hb,
          int* __restrict__ ctrl) {
  __shared__ __align__(16) char smem[131072];   // only 16KB used; size forces 1 block/CU
  __shared__ int s_rank;

  int* ticket = ctrl + 512;    // ints [512,520): per-XCD ticket counters

  const int tid  = threadIdx.x;
  const int lane = tid & 63;
  const int wv   = tid >> 6;
  const int l15  = lane & 15;
  const int l4   = lane >> 4;

  // ---- team = own XCD; rank = arrival order within the XCD ----
  int xcc;
  asm volatile("s_getreg_b32 %0, hwreg(HW_REG_XCC_ID)" : "=s"(xcc));
  if (tid == 0)
    s_rank = __hip_atomic_fetch_add(&ticket[xcc], 1, __ATOMIC_RELAXED,
                                    __HIP_MEMORY_SCOPE_AGENT);
  __syncthreads();
  const int rank = s_rank;
  if (rank >= TEAM) return;            // paranoia: uniform 32 CUs/XCD expected
  const int team  = xcc;
  int* arrive = ctrl + team * 64;      // 32 flags in this team's own cache line
  const int nbase = team * 16;         // team's batch rows [nbase, nbase+16)

  const unsigned long long t0 = rtclock();   // watchdog epoch

  // ---- W fragments: wave wv owns hidden units rank*16 + wv*4 + {0..3} ----
  // A-frag row l15 -> gate-col c = (rank*16+wv*4)*4 + l15; j = c>>2, g = c&3.
  const int g = l15 & 3;
  const float* Wg = (g == 0) ? Wi : (g == 1) ? Wf : (g == 2) ? Wo : Wh;
  const int jcol = rank * 16 + wv * 4 + (l15 >> 2);
  short8 bfrag[24];
#pragma unroll
  for (int kt = 0; kt < 24; ++kt) {
    union { short8 s; unsigned short us[8]; } cv;
#pragma unroll
    for (int e = 0; e < 8; ++e) {
      int k = kt * 32 + l4 * 8 + e;
      cv.us[e] = f2bf(Wg[(size_t)k * HIDN + jcol]);
    }
    bfrag[kt] = cv.s;
  }

  const int jglob = rank * 16 + wv * 4 + l4;   // hidden unit of this lane's D-col
  const float bI = bi[jglob], bF = bf_[jglob], bO = bo[jglob], bH = bh[jglob];
  float c = 0.f;

  unsigned short* hcur = hb;                   // zeroed by host memset: h_0 = 0
  unsigned short* hnxt = hb + (size_t)NB * HIDN;

  const int n = nbase + l15;                   // this lane's batch row (D col = l15)

  // ---- acc preloaded with x-GEMM for t=0 ----
  floatx4 acc = {0.f, 0.f, 0.f, 0.f};
  {
    short8 xq[8];
    if (USE_XE) {
      const unsigned short* xr = xe + (size_t)n * EMB + l4 * 8;
#pragma unroll
      for (int kt = 0; kt < 8; ++kt) xq[kt] = *(const short8*)(xr + kt * 32);
    } else {
      int idx = X[(size_t)n * LSEQ + 0];
      const float* er = E + (size_t)idx * EMB + l4 * 8;
#pragma unroll
      for (int kt = 0; kt < 8; ++kt) {
        float4 u = *(const float4*)(er + kt * 32);
        float4 v = *(const float4*)(er + kt * 32 + 4);
        xq[kt] = pack8(u, v);
      }
    }
#pragma unroll
    for (int kt = 0; kt < 8; ++kt)
      acc = __builtin_amdgcn_mfma_f32_16x16x32_bf16(bfrag[16 + kt], xq[kt], acc, 0, 0, 0);
  }

  const int swz = (l15 & 7) << 4;              // read swizzle: local row == l15

  for (int t = 0; t < LSEQ; ++t) {
    // ---- stage h(t): wave wv pulls team-local rows [wv*4, wv*4+4) ----
    // one fully-coalesced 1KB row per instruction (lane covers bytes lane*16)
    short8 pv[4];
    const char* hrow = (const char*)hcur + (size_t)(nbase + wv * 4) * (HIDN * 2) + lane * 16;
#pragma unroll
    for (int cc = 0; cc < 4; ++cc)
      pv[cc] = ld16_sc0(hrow + cc * 1024);
    asm volatile("s_waitcnt vmcnt(0)" ::: "memory");
#pragma unroll
    for (int cc = 0; cc < 4; ++cc) {
      int rl = wv * 4 + cc;                    // LDS-local row
      *(short8*)(smem + ((rl * 1024 + lane * 16) ^ ((rl & 7) << 4))) = pv[cc];
    }
    __syncthreads();                           // A: 16-row tile staged

    // ---- h-GEMM: 16 kt, 1 ds_read + 1 MFMA each ----
#pragma unroll
    for (int kt = 0; kt < 16; ++kt) {
      short8 hq = *(const short8*)(smem + ((l15 * 1024 + kt * 64 + l4 * 16) ^ swz));
      acc = __builtin_amdgcn_mfma_f32_16x16x32_bf16(bfrag[kt], hq, acc, 0, 0, 0);
    }

    // ---- gates: lane (l15,l4) -> h[n][jglob] ----
    float ig = sigmoid_f(acc[0] + bI);
    float fg = sigmoid_f(acc[1] + bF);
    float og = sigmoid_f(acc[2] + bO);
    float gg = tanh_f(acc[3] + bH);
    c = fg * c + ig * gg;
    float hv = og * tanh_f(c);

    // ---- h(t+1) store: pack (j, j+1) across lane^16; even-l4 lanes store 4B
    unsigned w  = (unsigned)f2bf(hv);
    unsigned wp = (unsigned)__builtin_amdgcn_ds_swizzle((int)w, 0x401F); // xor 16
    if ((l4 & 1) == 0) {
      unsigned val = w | (wp << 16);
      unsigned* p = (unsigned*)(hnxt + (size_t)n * HIDN + jglob);
      __hip_atomic_store(p, val, __ATOMIC_RELAXED, __HIP_MEMORY_SCOPE_WORKGROUP);
    }

    if (t == LSEQ - 1) {
      out[(size_t)n * HIDN + jglob] = hv;
      break;
    }

    { unsigned short* tmp = hcur; hcur = hnxt; hnxt = tmp; }

    const int gen = t + 1;
    // B: each wave drains its own stores (vmcnt 0) before the barrier, so all
    // h stores are L2-visible before tid0's flag. Also orders LDS reads
    // before next step's ds_writes.
    __syncthreads();
    if (tid == 0)
      __hip_atomic_store(&arrive[rank], gen, __ATOMIC_RELAXED,
                         __HIP_MEMORY_SCOPE_WORKGROUP);

    // ---- off-chain: x-GEMM for t+1 while teammates arrive ----
    {
      short8 xq[8];
      if (USE_XE) {
        const unsigned short* xr = xe + ((size_t)(t + 1) * NB + n) * EMB + l4 * 8;
#pragma unroll
        for (int kt = 0; kt < 8; ++kt) xq[kt] = *(const short8*)(xr + kt * 32);
      } else {
        int idx = X[(size_t)n * LSEQ + t + 1];
        const float* er = E + (size_t)idx * EMB + l4 * 8;
#pragma unroll
        for (int kt = 0; kt < 8; ++kt) {
          float4 u = *(const float4*)(er + kt * 32);
          float4 v = *(const float4*)(er + kt * 32 + 4);
          xq[kt] = pack8(u, v);
        }
      }
      acc = floatx4{0.f, 0.f, 0.f, 0.f};
#pragma unroll
      for (int kt = 0; kt < 8; ++kt)
        acc = __builtin_amdgcn_mfma_f32_16x16x32_bf16(bfrag[16 + kt], xq[kt], acc, 0, 0, 0);
    }

    // ---- poll own team's 32 flags (one L2 line); lane spins on flag lane&31.
    //      Deadline-bounded: on sync failure we fall through (finite, wrong
    //      answer) instead of wedging the GPU.
    {
      const int* fp = &arrive[lane & 31];
      int va;
      do {
        va = ld_flag_sc0(fp);
        if (rtclock() - t0 > DEADLINE_TICKS) break;
      } while (va < gen);
    }
    __atomic_signal_fence(__ATOMIC_ACQUIRE);  // compiler barrier only
  }
}

// ws layout: [0, 2048) team flags (8 teams x 64 ints, 32 used each),
// [2048, 2080) tickets, zeroed to 8192; [8192, +262144) h double buffer;
// then (optional, if ws_size permits) xe bf16 time-major (33.5 MB).
extern "C" void kernel_launch(void* const* d_in, const int* in_sizes, int n_in,
                              void* d_out, int out_size, void* d_ws, size_t ws_size,
                              hipStream_t stream) {
  const int*   X  = (const int*)d_in[0];
  const float* E  = (const float*)d_in[1];
  const float* Wi = (const float*)d_in[2];
  const float* bi = (const float*)d_in[3];
  const float* Wf = (const float*)d_in[4];
  const float* bf = (const float*)d_in[5];
  const float* Wo = (const float*)d_in[6];
  const float* bo = (const float*)d_in[7];
  const float* Wh = (const float*)d_in[8];
  const float* bh = (const float*)d_in[9];
  float* out = (float*)d_out;

  char* ws = (char*)d_ws;
  int* ctrl = (int*)ws;
  unsigned short* hb = (unsigned short*)(ws + 8192);
  const size_t xe_off = 8192 + 2 * (size_t)NB * HIDN * sizeof(unsigned short);
  const size_t xe_bytes = (size_t)LSEQ * NB * EMB * sizeof(unsigned short);
  const bool use_xe = ws_size >= xe_off + xe_bytes;
  unsigned short* xe = use_xe ? (unsigned short*)(ws + xe_off) : nullptr;

  hipMemsetAsync(ws, 0, xe_off, stream);  // zero flags/tickets + h_0

  if (use_xe)
    prep_x_kernel<<<dim3(LSEQ, NB), dim3(64), 0, stream>>>(X, E, xe);

  if (use_xe)
    lstm_main<true><<<dim3(GRID_ALL), dim3(256), 0, stream>>>(
        X, E, xe, Wi, bi, Wf, bf, Wo, bo, Wh, bh, out, hb, ctrl);
  else
    lstm_main<false><<<dim3(GRID_ALL), dim3(256), 0, stream>>>(
        X, E, xe, Wi, bi, Wf, bf, Wo, bo, Wh, bh, out, hb, ctrl);
}

// Round 9
// 1443.695 us; speedup vs baseline: 173.9985x; 173.9985x over previous
//
#include <hip/hip_runtime.h>
#include <hip/hip_bf16.h>

#define NB    128
#define LSEQ  512
#define HIDN  512
#define EMB   256
#define GRID_ALL 256    // one block per CU (forced by 128KB LDS); 32 per XCD
#define TEAM  32        // blocks per team; team == XCD; rank owns hidden units [rank*16, +16)
#define DEADLINE_TICKS 25000000ull   // s_memrealtime watchdog: finite even on sync failure

typedef __attribute__((ext_vector_type(8))) short  short8;   // MFMA A/B frag (8 bf16)
typedef __attribute__((ext_vector_type(4))) float  floatx4;  // MFMA C/D frag
typedef __attribute__((ext_vector_type(4))) unsigned int uintx4;

__device__ __forceinline__ unsigned short f2bf(float f) {   // RNE
  unsigned u = __builtin_bit_cast(unsigned, f);
  unsigned r = u + 0x7fffu + ((u >> 16) & 1u);
  return (unsigned short)(r >> 16);
}
__device__ __forceinline__ unsigned bfpair(float lo, float hi) {
  unsigned a = __builtin_bit_cast(unsigned, lo) + 0x8000u;
  unsigned b = __builtin_bit_cast(unsigned, hi) + 0x8000u;
  return __builtin_amdgcn_perm(b, a, 0x07060302u);
}
__device__ __forceinline__ short8 pack8(float4 u, float4 v) {
  union { short8 s; uintx4 w; } cv;
  cv.w[0] = bfpair(u.x, u.y); cv.w[1] = bfpair(u.z, u.w);
  cv.w[2] = bfpair(v.x, v.y); cv.w[3] = bfpair(v.z, v.w);
  return cv.s;
}
__device__ __forceinline__ float sigmoid_f(float x) { return 1.f / (1.f + __expf(-x)); }
__device__ __forceinline__ float tanh_f(float x) {
  float e = __expf(2.f * x);
  return 1.f - 2.f / (e + 1.f);
}

// R1-PROVEN cross-block protocol: agent-scope atomics for EVERY cross-block
// load/store. R8 proved workgroup-scope stores + sc0 loads are NOT a reliable
// channel: the flag store lingered in the producer CU's store path and the
// polled line never turned over -> all 8 teams spun to the watchdog deadline
// (dur == deadline exactly, occupancy 12.5% throughout). R5 only "worked"
// because 128KB/step of traffic forced line turnover. Agent atomics carry
// proper cache-control bits -> always visible.
__device__ __forceinline__ short8 pull16(const unsigned long long* p) {
  union { unsigned long long u[2]; short8 s; } r;
  r.u[0] = __hip_atomic_load(p,     __ATOMIC_RELAXED, __HIP_MEMORY_SCOPE_AGENT);
  r.u[1] = __hip_atomic_load(p + 1, __ATOMIC_RELAXED, __HIP_MEMORY_SCOPE_AGENT);
  return r.s;
}
__device__ __forceinline__ unsigned long long rtclock() {
  unsigned long long v;
  asm volatile("s_memrealtime %0\n\ts_waitcnt lgkmcnt(0)" : "=s"(v));
  return v;
}

// xe[t][n][e] = bf16(E[X[n][t]][e]) — time-major, k-contiguous
__global__ void prep_x_kernel(const int* __restrict__ X, const float* __restrict__ E,
                              unsigned short* __restrict__ xe) {
  int t = blockIdx.x, n = blockIdx.y;
  int row = X[(size_t)n * LSEQ + t];
  float4 v = ((const float4*)(E + (size_t)row * EMB))[threadIdx.x];
  ushort4 o;
  o.x = f2bf(v.x); o.y = f2bf(v.y); o.z = f2bf(v.z); o.w = f2bf(v.w);
  *(ushort4*)(xe + ((size_t)t * NB + n) * EMB + threadIdx.x * 4) = o;
}

// ---- main recurrence: 8 INDEPENDENT teams (one per XCD) --------------------
// Team formation + full 256-block residency PROVEN by R8 (occupancy 12.46%
// for the whole run; every block got rank<32). Per-CU per-step: 16KB h pull
// (coalesced agent loads) + 16KB LDS tile + 24 MFMA — 8x less communication
// and 8x fewer MFMA than the ~10.6us/step structures. Teams never interact.
// Every spin is deadline-bounded (wedge insurance; R6/R7 were GPU wedges).
template <bool USE_XE>
__global__ void __launch_bounds__(256, 1)
lstm_main(const int* __restrict__ X, const float* __restrict__ E,
          const unsigned short* __restrict__ xe,
          const float* __restrict__ Wi, const float* __restrict__ bi,
          const float* __restrict__ Wf, const float* __restrict__ bf_,
          const float* __restrict__ Wo, const float* __restrict__ bo,
          const float* __restrict__ Wh, const float* __restrict__ bh,
          float* __restrict__ out, unsigned short* __restrict__ hb,
          int* __restrict__ ctrl) {
  __shared__ __align__(16) char smem[131072];   // only 16KB used; size forces 1 block/CU
  __shared__ int s_rank;

  int* ticket = ctrl + 512;    // ints [512,520): per-XCD ticket counters

  const int tid  = threadIdx.x;
  const int lane = tid & 63;
  const int wv   = tid >> 6;
  const int l15  = lane & 15;
  const int l4   = lane >> 4;

  // ---- team = own XCD; rank = arrival order within the XCD ----
  int xcc;
  asm volatile("s_getreg_b32 %0, hwreg(HW_REG_XCC_ID)" : "=s"(xcc));
  if (tid == 0)
    s_rank = __hip_atomic_fetch_add(&ticket[xcc], 1, __ATOMIC_RELAXED,
                                    __HIP_MEMORY_SCOPE_AGENT);
  __syncthreads();
  const int rank = s_rank;
  if (rank >= TEAM) return;            // paranoia: R8 showed uniform 32/XCD
  const int team  = xcc;
  int* arrive = ctrl + team * 64;      // 32 flags = one 128B line per team
  const int nbase = team * 16;         // team's batch rows [nbase, nbase+16)

  const unsigned long long t0 = rtclock();   // watchdog epoch

  // ---- W fragments: wave wv owns hidden units rank*16 + wv*4 + {0..3} ----
  // A-frag row l15 -> gate-col c = (rank*16+wv*4)*4 + l15; j = c>>2, g = c&3.
  const int g = l15 & 3;
  const float* Wg = (g == 0) ? Wi : (g == 1) ? Wf : (g == 2) ? Wo : Wh;
  const int jcol = rank * 16 + wv * 4 + (l15 >> 2);
  short8 bfrag[24];
#pragma unroll
  for (int kt = 0; kt < 24; ++kt) {
    union { short8 s; unsigned short us[8]; } cv;
#pragma unroll
    for (int e = 0; e < 8; ++e) {
      int k = kt * 32 + l4 * 8 + e;
      cv.us[e] = f2bf(Wg[(size_t)k * HIDN + jcol]);
    }
    bfrag[kt] = cv.s;
  }

  const int jglob = rank * 16 + wv * 4 + l4;   // hidden unit of this lane's D-col
  const float bI = bi[jglob], bF = bf_[jglob], bO = bo[jglob], bH = bh[jglob];
  float c = 0.f;

  unsigned short* hcur = hb;                   // zeroed by host memset: h_0 = 0
  unsigned short* hnxt = hb + (size_t)NB * HIDN;

  const int n = nbase + l15;                   // this lane's batch row (D col = l15)

  // ---- acc preloaded with x-GEMM for t=0 ----
  floatx4 acc = {0.f, 0.f, 0.f, 0.f};
  {
    short8 xq[8];
    if (USE_XE) {
      const unsigned short* xr = xe + (size_t)n * EMB + l4 * 8;
#pragma unroll
      for (int kt = 0; kt < 8; ++kt) xq[kt] = *(const short8*)(xr + kt * 32);
    } else {
      int idx = X[(size_t)n * LSEQ + 0];
      const float* er = E + (size_t)idx * EMB + l4 * 8;
#pragma unroll
      for (int kt = 0; kt < 8; ++kt) {
        float4 u = *(const float4*)(er + kt * 32);
        float4 v = *(const float4*)(er + kt * 32 + 4);
        xq[kt] = pack8(u, v);
      }
    }
#pragma unroll
    for (int kt = 0; kt < 8; ++kt)
      acc = __builtin_amdgcn_mfma_f32_16x16x32_bf16(bfrag[16 + kt], xq[kt], acc, 0, 0, 0);
  }

  const int swz = (l15 & 7) << 4;              // read swizzle: local row == l15

  for (int t = 0; t < LSEQ; ++t) {
    // ---- stage h(t): wave wv pulls team rows [wv*4, wv*4+4) ----
    // agent-scope 16B pulls; lane covers bytes [lane*16, +16) of the 1KB row
    // -> fully coalesced; all 8 underlying loads pipeline in one round-trip.
    short8 pv[4];
    const unsigned long long* hbase =
        (const unsigned long long*)(hcur + (size_t)(nbase + wv * 4) * HIDN);
#pragma unroll
    for (int cc = 0; cc < 4; ++cc)
      pv[cc] = pull16(hbase + cc * 128 + lane * 2);
#pragma unroll
    for (int cc = 0; cc < 4; ++cc) {
      int rl = wv * 4 + cc;                    // LDS-local row
      *(short8*)(smem + ((rl * 1024 + lane * 16) ^ ((rl & 7) << 4))) = pv[cc];
    }
    __syncthreads();                           // A: 16-row tile staged

    // ---- h-GEMM: 16 kt, 1 ds_read + 1 MFMA each ----
#pragma unroll
    for (int kt = 0; kt < 16; ++kt) {
      short8 hq = *(const short8*)(smem + ((l15 * 1024 + kt * 64 + l4 * 16) ^ swz));
      acc = __builtin_amdgcn_mfma_f32_16x16x32_bf16(bfrag[kt], hq, acc, 0, 0, 0);
    }

    // ---- gates: lane (l15,l4) -> h[n][jglob] ----
    float ig = sigmoid_f(acc[0] + bI);
    float fg = sigmoid_f(acc[1] + bF);
    float og = sigmoid_f(acc[2] + bO);
    float gg = tanh_f(acc[3] + bH);
    c = fg * c + ig * gg;
    float hv = og * tanh_f(c);

    // ---- h(t+1) store: pack (j, j+1) across lane^16; even-l4 lanes store 4B
    //      AGENT scope: write-through past the CU store path (R8 lesson).
    unsigned w  = (unsigned)f2bf(hv);
    unsigned wp = (unsigned)__builtin_amdgcn_ds_swizzle((int)w, 0x401F); // xor 16
    if ((l4 & 1) == 0) {
      unsigned val = w | (wp << 16);
      unsigned* p = (unsigned*)(hnxt + (size_t)n * HIDN + jglob);
      __hip_atomic_store(p, val, __ATOMIC_RELAXED, __HIP_MEMORY_SCOPE_AGENT);
    }

    if (t == LSEQ - 1) {
      out[(size_t)n * HIDN + jglob] = hv;
      break;
    }

    { unsigned short* tmp = hcur; hcur = hnxt; hnxt = tmp; }

    const int gen = t + 1;
    // B: barrier drains vmcnt(0) -> all h stores are at the coherence point
    // before tid0's flag store issues. Also orders this step's LDS reads
    // before next step's ds_writes.
    __syncthreads();
    if (tid == 0)
      __hip_atomic_store(&arrive[rank], gen, __ATOMIC_RELAXED,
                         __HIP_MEMORY_SCOPE_AGENT);

    // ---- off-chain: x-GEMM for t+1 while teammates arrive ----
    {
      short8 xq[8];
      if (USE_XE) {
        const unsigned short* xr = xe + ((size_t)(t + 1) * NB + n) * EMB + l4 * 8;
#pragma unroll
        for (int kt = 0; kt < 8; ++kt) xq[kt] = *(const short8*)(xr + kt * 32);
      } else {
        int idx = X[(size_t)n * LSEQ + t + 1];
        const float* er = E + (size_t)idx * EMB + l4 * 8;
#pragma unroll
        for (int kt = 0; kt < 8; ++kt) {
          float4 u = *(const float4*)(er + kt * 32);
          float4 v = *(const float4*)(er + kt * 32 + 4);
          xq[kt] = pack8(u, v);
        }
      }
      acc = floatx4{0.f, 0.f, 0.f, 0.f};
#pragma unroll
      for (int kt = 0; kt < 8; ++kt)
        acc = __builtin_amdgcn_mfma_f32_16x16x32_bf16(bfrag[16 + kt], xq[kt], acc, 0, 0, 0);
    }

    // ---- poll own team's 32 flags (one line); agent-scope atomic loads.
    //      Deadline-bounded: sync failure -> finite wrong answer, not a wedge.
    {
      const int* fp = &arrive[lane & 31];
      int va;
      do {
        va = __hip_atomic_load(fp, __ATOMIC_RELAXED, __HIP_MEMORY_SCOPE_AGENT);
        if (rtclock() - t0 > DEADLINE_TICKS) break;
      } while (va < gen);
    }
    __atomic_signal_fence(__ATOMIC_ACQUIRE);  // compiler barrier only
  }
}

// ws layout: [0, 2048) team flags (8 teams x 64 ints, 32 used each),
// [2048, 2080) tickets, zeroed to 8192; [8192, +262144) h double buffer;
// then (optional, if ws_size permits) xe bf16 time-major (33.5 MB).
extern "C" void kernel_launch(void* const* d_in, const int* in_sizes, int n_in,
                              void* d_out, int out_size, void* d_ws, size_t ws_size,
                              hipStream_t stream) {
  const int*   X  = (const int*)d_in[0];
  const float* E  = (const float*)d_in[1];
  const float* Wi = (const float*)d_in[2];
  const float* bi = (const float*)d_in[3];
  const float* Wf = (const float*)d_in[4];
  const float* bf = (const float*)d_in[5];
  const float* Wo = (const float*)d_in[6];
  const float* bo = (const float*)d_in[7];
  const float* Wh = (const float*)d_in[8];
  const float* bh = (const float*)d_in[9];
  float* out = (float*)d_out;

  char* ws = (char*)d_ws;
  int* ctrl = (int*)ws;
  unsigned short* hb = (unsigned short*)(ws + 8192);
  const size_t xe_off = 8192 + 2 * (size_t)NB * HIDN * sizeof(unsigned short);
  const size_t xe_bytes = (size_t)LSEQ * NB * EMB * sizeof(unsigned short);
  const bool use_xe = ws_size >= xe_off + xe_bytes;
  unsigned short* xe = use_xe ? (unsigned short*)(ws + xe_off) : nullptr;

  hipMemsetAsync(ws, 0, xe_off, stream);  // zero flags/tickets + h_0

  if (use_xe)
    prep_x_kernel<<<dim3(LSEQ, NB), dim3(64), 0, stream>>>(X, E, xe);

  if (use_xe)
    lstm_main<true><<<dim3(GRID_ALL), dim3(256), 0, stream>>>(
        X, E, xe, Wi, bi, Wf, bf, Wo, bo, Wh, bh, out, hb, ctrl);
  else
    lstm_main<false><<<dim3(GRID_ALL), dim3(256), 0, stream>>>(
        X, E, xe, Wi, bi, Wf, bf, Wo, bo, Wh, bh, out, hb, ctrl);
}